// Round 3
// baseline (1396.031 us; speedup 1.0000x reference)
//
#include <hip/hip_runtime.h>
#include <hip/hip_bf16.h>
#include <stdint.h>

// Problem constants (SNNExoplanetDetector): B=256 batch, T=1000 steps,
// F=128 input feats, H=256 hidden, O=2 outputs.
constexpr int B = 256, T = 1000, F = 128, H = 256, O = 2;
constexpr float DT_TAU_MEM = 0.1f;   // DT * TAU_MEM_INV
constexpr float SYN_DECAY  = 0.8f;   // 1 - DT * TAU_SYN_INV
constexpr float V_THRESH   = 1.0f;

// ---------------------------------------------------------------------------
// Storage-type adapters for xw (fp32 if workspace fits it, else bf16).
// ---------------------------------------------------------------------------
__device__ inline unsigned short f2bf_raw(float f) {
  __hip_bfloat16 b = __float2bfloat16(f);
  return *reinterpret_cast<unsigned short*>(&b);
}

template <typename XT> struct XConv;
template <> struct XConv<float> {
  static __device__ inline float4 load4(const float* p) {
    return *reinterpret_cast<const float4*>(p);
  }
  static __device__ inline void store4(float* p, float a, float b, float c, float d) {
    *reinterpret_cast<float4*>(p) = make_float4(a, b, c, d);
  }
};
template <> struct XConv<__hip_bfloat16> {
  static __device__ inline float4 load4(const __hip_bfloat16* p) {
    ushort4 u = *reinterpret_cast<const ushort4*>(p);
    return make_float4(__uint_as_float((unsigned)u.x << 16),
                       __uint_as_float((unsigned)u.y << 16),
                       __uint_as_float((unsigned)u.z << 16),
                       __uint_as_float((unsigned)u.w << 16));
  }
  static __device__ inline void store4(__hip_bfloat16* p, float a, float b, float c, float d) {
    ushort4 u = make_ushort4(f2bf_raw(a), f2bf_raw(b), f2bf_raw(c), f2bf_raw(d));
    *reinterpret_cast<ushort4*>(p) = u;
  }
};

// ---------------------------------------------------------------------------
// Transpose w_rec [h][k] -> wT [k][h]  (so a spike k gathers a contiguous row)
// ---------------------------------------------------------------------------
__global__ void transpose_wrec(const float* __restrict__ w, float* __restrict__ wT) {
  int k = blockIdx.x;
  int h = threadIdx.x;
  wT[k * H + h] = w[h * H + k];
}

// ---------------------------------------------------------------------------
// GEMM: xw[m][n] = sum_k x[m][k] * w_in[n][k];  M = B*T = 256000, K=128, N=256
// (unchanged from previous best kernel)
// ---------------------------------------------------------------------------
template <typename XT>
__global__ __launch_bounds__(256) void gemm_xw(const float* __restrict__ x,
                                               const float* __restrict__ w_in,
                                               XT* __restrict__ xw) {
  constexpr int K = 128;
  constexpr int SA = 68;  // padded LDS row stride (floats), multiple of 4 for b128
  __shared__ float As[K][SA];
  __shared__ float Bs[K][SA];

  const int m0 = blockIdx.x * 64;
  const int n0 = blockIdx.y * 64;
  const int tid = threadIdx.x;

  {
    const int r  = tid >> 2;   // 0..63  (row within tile)
    const int cq = tid & 3;    // 0..3   (float4 phase)
    const float* xa = x    + (size_t)(m0 + r) * K;
    const float* xb = w_in + (size_t)(n0 + r) * K;
#pragma unroll
    for (int j = 0; j < 8; ++j) {
      const int c = (cq + (j << 2)) << 2;  // 0..124, step covers all 128
      float4 av = *reinterpret_cast<const float4*>(xa + c);
      float4 bv = *reinterpret_cast<const float4*>(xb + c);
      As[c + 0][r] = av.x; As[c + 1][r] = av.y; As[c + 2][r] = av.z; As[c + 3][r] = av.w;
      Bs[c + 0][r] = bv.x; Bs[c + 1][r] = bv.y; Bs[c + 2][r] = bv.z; Bs[c + 3][r] = bv.w;
    }
  }
  __syncthreads();

  const int tn = (tid & 15) << 2;  // 0,4,...,60
  const int tm = (tid >> 4) << 2;  // 0,4,...,60
  float acc[4][4] = {};

#pragma unroll 16
  for (int k = 0; k < K; ++k) {
    float4 a = *reinterpret_cast<const float4*>(&As[k][tm]);
    float4 b = *reinterpret_cast<const float4*>(&Bs[k][tn]);
    acc[0][0] += a.x * b.x; acc[0][1] += a.x * b.y; acc[0][2] += a.x * b.z; acc[0][3] += a.x * b.w;
    acc[1][0] += a.y * b.x; acc[1][1] += a.y * b.y; acc[1][2] += a.y * b.z; acc[1][3] += a.y * b.w;
    acc[2][0] += a.z * b.x; acc[2][1] += a.z * b.y; acc[2][2] += a.z * b.z; acc[2][3] += a.z * b.w;
    acc[3][0] += a.w * b.x; acc[3][1] += a.w * b.y; acc[3][2] += a.w * b.z; acc[3][3] += a.w * b.w;
  }

#pragma unroll
  for (int im = 0; im < 4; ++im) {
    XT* p = xw + (size_t)(m0 + tm + im) * H + (n0 + tn);
    XConv<XT>::store4(p, acc[im][0], acc[im][1], acc[im][2], acc[im][3]);
  }
}

// ---------------------------------------------------------------------------
// LIF scan, single-wave design:
//   one wave (64 threads) per batch element; thread t owns neurons 4t..4t+3.
//   Spike exchange = four __ballot's -> four wave-uniform 64-bit masks in
//   SGPRs. NO barriers, NO LDS spike list, NO atomics in the T-loop.
//   wT rows 0..127 staged in LDS (exact fp32, 128 KB); rows 128..255 gathered
//   from L2. Masks split lo/hi so each stream's rows map to one source.
//   Gather: chunks of 8 rows, scalar-pipe bit extraction, predicated FMA
//   (pred is wave-uniform -> cheap), global stream 2-deep software-pipelined
//   (>=8 float4 loads in flight).
// ---------------------------------------------------------------------------

// Extract one row index from a 2x64-bit mask stream (wave-uniform -> SALU).
// Stream packed as X = mask_j0 | mask_j1<<32, Y = mask_j2 | mask_j3<<32,
// bit p of word w meaning neuron 4*(p&31) + j(w):  row = ((p&31)<<2) | j.
// ctz guard: OR with the TOP bit (not bit 0!) -- leaves the lowest set bit of
// any nonzero mask untouched; empty mask decodes p_=63 -> dummy row 125/127,
// in-bounds and predicated off. (Round-2 bug: `sel_|1` made ctz()==0 always.)
#define EX1(X, Y, ROW) do {                                         \
    uint64_t sel_ = (X) ? (X) : (Y);                                \
    int p_ = __builtin_ctzll(sel_ | 0x8000000000000000ull);         \
    ROW = ((p_ & 31) << 2) | (p_ >> 5) | ((X) ? 0 : 2);             \
    uint64_t cl_ = sel_ & (sel_ - 1ull);                            \
    Y = (X) ? (Y) : cl_;                                            \
    X = (X) ? cl_ : (X);                                            \
  } while (0)

// Extract up to 8 rows, issue 8 float4 loads from BASE[row<<6], preds from N.
#define CHUNK8(X, Y, N, BASE, V0,V1,V2,V3,V4,V5,V6,V7, P0,P1,P2,P3,P4,P5,P6,P7) do { \
    int r_;                                                          \
    P0 = ((N) > 0) ? 1.f : 0.f; EX1(X, Y, r_); V0 = (BASE)[r_ << 6]; \
    P1 = ((N) > 1) ? 1.f : 0.f; EX1(X, Y, r_); V1 = (BASE)[r_ << 6]; \
    P2 = ((N) > 2) ? 1.f : 0.f; EX1(X, Y, r_); V2 = (BASE)[r_ << 6]; \
    P3 = ((N) > 3) ? 1.f : 0.f; EX1(X, Y, r_); V3 = (BASE)[r_ << 6]; \
    P4 = ((N) > 4) ? 1.f : 0.f; EX1(X, Y, r_); V4 = (BASE)[r_ << 6]; \
    P5 = ((N) > 5) ? 1.f : 0.f; EX1(X, Y, r_); V5 = (BASE)[r_ << 6]; \
    P6 = ((N) > 6) ? 1.f : 0.f; EX1(X, Y, r_); V6 = (BASE)[r_ << 6]; \
    P7 = ((N) > 7) ? 1.f : 0.f; EX1(X, Y, r_); V7 = (BASE)[r_ << 6]; \
  } while (0)

#define ACC8(V0,V1,V2,V3,V4,V5,V6,V7, P0,P1,P2,P3,P4,P5,P6,P7) do {  \
    r0 += P0 * V0.x; r1 += P0 * V0.y; r2 += P0 * V0.z; r3 += P0 * V0.w; \
    r0 += P1 * V1.x; r1 += P1 * V1.y; r2 += P1 * V1.z; r3 += P1 * V1.w; \
    r0 += P2 * V2.x; r1 += P2 * V2.y; r2 += P2 * V2.z; r3 += P2 * V2.w; \
    r0 += P3 * V3.x; r1 += P3 * V3.y; r2 += P3 * V3.z; r3 += P3 * V3.w; \
    r0 += P4 * V4.x; r1 += P4 * V4.y; r2 += P4 * V4.z; r3 += P4 * V4.w; \
    r0 += P5 * V5.x; r1 += P5 * V5.y; r2 += P5 * V5.z; r3 += P5 * V5.w; \
    r0 += P6 * V6.x; r1 += P6 * V6.y; r2 += P6 * V6.z; r3 += P6 * V6.w; \
    r0 += P7 * V7.x; r1 += P7 * V7.y; r2 += P7 * V7.z; r3 += P7 * V7.w; \
  } while (0)

template <typename XT>
__global__ __launch_bounds__(64, 1) void scan_lif(const XT* __restrict__ xw,
                                                  const float* __restrict__ wT,
                                                  const float* __restrict__ fc_w,
                                                  const float* __restrict__ fc_b,
                                                  float* __restrict__ out) {
  const int b  = blockIdx.x;
  const int ln = threadIdx.x;  // lane 0..63; owns neurons 4ln..4ln+3

  // Rows 0..127 of wT, exact fp32, laid out [row][lane] as float4 (cols 4ln..4ln+3).
  __shared__ float4 wlds[128 * 64];  // 128 KiB (legal on gfx950: 160 KiB/CU)

  const float4* wTf4 = reinterpret_cast<const float4*>(wT);
  for (int i = ln; i < 128 * 64; i += 64) wlds[i] = wTf4[i];
  __syncthreads();

  const float4* gB = wTf4 + 128 * 64 + ln;  // rows 128..255 via gB[row<<6]
  const float4* lB = &wlds[ln];             // rows 0..127  via lB[row<<6]

  float v0 = 0.f, v1 = 0.f, v2 = 0.f, v3 = 0.f;   // membrane
  float c0 = 0.f, c1 = 0.f, c2 = 0.f, c3 = 0.f;   // synaptic current
  int   n0 = 0,   n1 = 0,   n2 = 0,   n3 = 0;     // spike counts
  unsigned long long mA = 0, mBm = 0, mC = 0, mD = 0;  // prev-step ballot masks

  const XT* xrow = xw + (size_t)b * T * H + (ln << 2);
  float4 xa = XConv<XT>::load4(xrow);
  float4 xb = XConv<XT>::load4(xrow + H);

#pragma unroll 1
  for (int tt = 0; tt < T; ++tt) {
    const float4 xt = xa;
    xa = xb;
    xb = (tt + 2 < T) ? XConv<XT>::load4(xrow + (size_t)(tt + 2) * H)
                      : make_float4(0.f, 0.f, 0.f, 0.f);

    // ---- recurrent gather over PREVIOUS step's spikes (reference uses carry z)
    // lo 32 bits of each mask = rows < 128 (LDS); hi 32 bits = rows >= 128 (L2).
    uint64_t Lx = (uint32_t)mA         | ((uint64_t)(uint32_t)mBm         << 32);
    uint64_t Ly = (uint32_t)mC         | ((uint64_t)(uint32_t)mD          << 32);
    uint64_t Gx = (uint32_t)(mA >> 32) | ((uint64_t)(uint32_t)(mBm >> 32) << 32);
    uint64_t Gy = (uint32_t)(mC >> 32) | ((uint64_t)(uint32_t)(mD  >> 32) << 32);
    int nl = __popcll(Lx) + __popcll(Ly);
    int ng = __popcll(Gx) + __popcll(Gy);

    float r0 = 0.f, r1 = 0.f, r2 = 0.f, r3 = 0.f;

    float4 g0, g1, g2, g3, g4, g5, g6, g7;
    float  q0, q1, q2, q3, q4, q5, q6, q7;
    float4 h0, h1, h2, h3, h4, h5, h6, h7;
    float  u0, u1, u2, u3, u4, u5, u6, u7;

    // Issue first global chunk early; its latency hides under the LDS chunks.
    const bool anyG = (ng > 0);
    if (anyG) {
      CHUNK8(Gx, Gy, ng, gB, g0,g1,g2,g3,g4,g5,g6,g7, q0,q1,q2,q3,q4,q5,q6,q7);
      ng -= 8;
    }

    // LDS stream (rows < 128): issue + consume per chunk (latency ~120cy, mostly
    // covered by the extraction/addressing work of the chunk itself).
    while (nl > 0) {
      float4 l0, l1, l2, l3, l4, l5, l6, l7;
      float  s0, s1, s2, s3, s4, s5, s6, s7;
      CHUNK8(Lx, Ly, nl, lB, l0,l1,l2,l3,l4,l5,l6,l7, s0,s1,s2,s3,s4,s5,s6,s7);
      nl -= 8;
      ACC8(l0,l1,l2,l3,l4,l5,l6,l7, s0,s1,s2,s3,s4,s5,s6,s7);
    }

    // Global stream (rows >= 128): 2-deep software pipeline, no register rotation.
    if (anyG) {
      for (;;) {
        if (ng <= 0) { ACC8(g0,g1,g2,g3,g4,g5,g6,g7, q0,q1,q2,q3,q4,q5,q6,q7); break; }
        CHUNK8(Gx, Gy, ng, gB, h0,h1,h2,h3,h4,h5,h6,h7, u0,u1,u2,u3,u4,u5,u6,u7);
        ng -= 8;
        ACC8(g0,g1,g2,g3,g4,g5,g6,g7, q0,q1,q2,q3,q4,q5,q6,q7);
        if (ng <= 0) { ACC8(h0,h1,h2,h3,h4,h5,h6,h7, u0,u1,u2,u3,u4,u5,u6,u7); break; }
        CHUNK8(Gx, Gy, ng, gB, g0,g1,g2,g3,g4,g5,g6,g7, q0,q1,q2,q3,q4,q5,q6,q7);
        ng -= 8;
        ACC8(h0,h1,h2,h3,h4,h5,h6,h7, u0,u1,u2,u3,u4,u5,u6,u7);
      }
    }

    // ---- LIF update (identical op order to previous absmax-0 kernel) ----
    const float vd0 = v0 + DT_TAU_MEM * (c0 - v0);
    const float vd1 = v1 + DT_TAU_MEM * (c1 - v1);
    const float vd2 = v2 + DT_TAU_MEM * (c2 - v2);
    const float vd3 = v3 + DT_TAU_MEM * (c3 - v3);
    const int z0 = vd0 > V_THRESH;
    const int z1 = vd1 > V_THRESH;
    const int z2 = vd2 > V_THRESH;
    const int z3 = vd3 > V_THRESH;
    v0 = z0 ? 0.f : vd0;  v1 = z1 ? 0.f : vd1;
    v2 = z2 ? 0.f : vd2;  v3 = z3 ? 0.f : vd3;
    c0 = c0 * SYN_DECAY + xt.x + r0;
    c1 = c1 * SYN_DECAY + xt.y + r1;
    c2 = c2 * SYN_DECAY + xt.z + r2;
    c3 = c3 * SYN_DECAY + xt.w + r3;
    n0 += z0; n1 += z1; n2 += z2; n3 += z3;

    mA  = __ballot(z0);  // neurons 4t+0 -> bit t
    mBm = __ballot(z1);  // neurons 4t+1
    mC  = __ballot(z2);  // neurons 4t+2
    mD  = __ballot(z3);  // neurons 4t+3
  }

  // ---- Readout: out[b][o] = sum_h count[h] * fc_w[o][h] + fc_b[o] ----
  const float4 f0 = *reinterpret_cast<const float4*>(fc_w + 0 * H + (ln << 2));
  const float4 f1 = *reinterpret_cast<const float4*>(fc_w + 1 * H + (ln << 2));
  float p0 = (float)n0 * f0.x + (float)n1 * f0.y + (float)n2 * f0.z + (float)n3 * f0.w;
  float p1 = (float)n0 * f1.x + (float)n1 * f1.y + (float)n2 * f1.z + (float)n3 * f1.w;
#pragma unroll
  for (int off = 32; off > 0; off >>= 1) {
    p0 += __shfl_down(p0, off, 64);
    p1 += __shfl_down(p1, off, 64);
  }
  if (ln == 0) {
    out[b * O + 0] = p0 + fc_b[0];
    out[b * O + 1] = p1 + fc_b[1];
  }
}

// ---------------------------------------------------------------------------
extern "C" void kernel_launch(void* const* d_in, const int* in_sizes, int n_in,
                              void* d_out, int out_size, void* d_ws, size_t ws_size,
                              hipStream_t stream) {
  const float* x     = (const float*)d_in[0];
  const float* w_in  = (const float*)d_in[1];
  const float* w_rec = (const float*)d_in[2];
  const float* fc_w  = (const float*)d_in[3];
  const float* fc_b  = (const float*)d_in[4];
  float* out = (float*)d_out;

  // workspace layout: [wT fp32 256KB][xw (fp32 if it fits, else bf16)]
  float* wT = (float*)d_ws;
  const size_t wT_bytes = (size_t)H * H * sizeof(float);
  char* xw_base = (char*)d_ws + wT_bytes;
  const size_t xw_elems = (size_t)B * T * H;
  const bool use_f32 = ws_size >= wT_bytes + xw_elems * sizeof(float);

  transpose_wrec<<<H, H, 0, stream>>>(w_rec, wT);

  if (use_f32) {
    float* xw = (float*)xw_base;
    gemm_xw<float><<<dim3(B * T / 64, H / 64), 256, 0, stream>>>(x, w_in, xw);
    scan_lif<float><<<B, 64, 0, stream>>>(xw, wT, fc_w, fc_b, out);
  } else {
    __hip_bfloat16* xw = (__hip_bfloat16*)xw_base;
    gemm_xw<__hip_bfloat16><<<dim3(B * T / 64, H / 64), 256, 0, stream>>>(x, w_in, xw);
    scan_lif<__hip_bfloat16><<<B, 64, 0, stream>>>(xw, wT, fc_w, fc_b, out);
  }
}